// Round 3
// baseline (3148.995 us; speedup 1.0000x reference)
//
#include <hip/hip_runtime.h>
#include <hip/hip_bf16.h>

#define DIM 128
#define XS_STRIDE (DIM + 4)   // 132 floats = 528 B: 16B-aligned rows (528 = 33*16)

// ---------------- degree / normalization ----------------

__global__ void deg_init(float* deg, int n) {
    int i = blockIdx.x * blockDim.x + threadIdx.x;
    if (i < n) deg[i] = 1.0f;   // self-loop contributes 1
}

__global__ void edge_deg(float* deg, const int* __restrict__ dst, int E) {
    int e = blockIdx.x * blockDim.x + threadIdx.x;
    if (e < E) unsafeAtomicAdd(&deg[dst[e]], 1.0f);
}

__global__ void deg_fin(float* deg, int n) {
    int i = blockIdx.x * blockDim.x + threadIdx.x;
    if (i < n) deg[i] = rsqrtf(deg[i]);   // deg >= 1 always
}

// ---------------- GEMM: Y[node][f] = sum_k X[node][k] * W[k][f] ----------------
// 64 nodes per block, 64 threads (1 wave), node-stationary: each thread owns one
// node's row (staged fp32 in LDS), loops 16 groups of 8 output features.
// W reads are wave-uniform (scalar-cache path). No bias on output (GCN adds bias
// after aggregation); MODE 1 applies relu(x + bias) on the *input* (prev layer
// epilogue fused into staging).

template<int MODE>   // 0: plain input; 1: input + bias + relu
__global__ __launch_bounds__(64) void gemm_nodes(
    const float* __restrict__ X,
    const float* __restrict__ bias,
    const float* __restrict__ W,   // [128][128] row-major (k, f), fp32
    float* __restrict__ Y, int N)
{
    __shared__ float xs[64][XS_STRIDE];
    const int t = threadIdx.x;          // 0..63
    const int node0 = blockIdx.x * 64;

    float bb0 = 0.f, bb1 = 0.f;
    if (MODE == 1) {
        bb0 = bias[t];
        bb1 = bias[t + 64];
    }
    for (int r = 0; r < 64; ++r) {
        int node = node0 + r;
        if (node < N) {
            float v0 = X[(size_t)node * DIM + t];
            float v1 = X[(size_t)node * DIM + t + 64];
            if (MODE == 1) {
                v0 = fmaxf(v0 + bb0, 0.f);
                v1 = fmaxf(v1 + bb1, 0.f);
            }
            xs[r][t]      = v0;
            xs[r][t + 64] = v1;
        } else {
            xs[r][t] = 0.f;
            xs[r][t + 64] = 0.f;
        }
    }
    __syncthreads();

    const int node = node0 + t;
    const bool valid = node < N;

    for (int g = 0; g < 16; ++g) {
        float acc[8] = {0.f,0.f,0.f,0.f,0.f,0.f,0.f,0.f};
        for (int k = 0; k < DIM; k += 4) {
            float4 xv = *(const float4*)&xs[t][k];   // 16B-aligned rows
            float xk[4] = {xv.x, xv.y, xv.z, xv.w};
            #pragma unroll
            for (int kk = 0; kk < 4; ++kk) {
                const float* wrow = W + (size_t)(k + kk) * DIM + g * 8; // uniform
                #pragma unroll
                for (int j = 0; j < 8; ++j) {
                    acc[j] = fmaf(xk[kk], wrow[j], acc[j]);
                }
            }
        }
        if (valid) {
            float4* outp = (float4*)&Y[(size_t)node * DIM + g * 8];
            outp[0] = make_float4(acc[0], acc[1], acc[2], acc[3]);
            outp[1] = make_float4(acc[4], acc[5], acc[6], acc[7]);
        }
    }
}

// ---------------- aggregation ----------------
// self-loop term initializes O (full overwrite — no memset needed),
// then edges scatter-add on top.

__global__ void self_loop(const float* __restrict__ H, float* __restrict__ O,
                          const float* __restrict__ dinv, int N)
{
    size_t tid = (size_t)blockIdx.x * blockDim.x + threadIdx.x;
    int i = (int)(tid >> 5);
    if (i >= N) return;
    int f = ((int)tid & 31) * 4;
    float di = dinv[i];
    float nrm = di * di;
    float4 hv = *(const float4*)&H[(size_t)i * DIM + f];
    float4 ov = make_float4(hv.x * nrm, hv.y * nrm, hv.z * nrm, hv.w * nrm);
    *(float4*)&O[(size_t)i * DIM + f] = ov;
}

__global__ void edge_agg(const float* __restrict__ H, float* __restrict__ O,
                         const int* __restrict__ src, const int* __restrict__ dst,
                         const float* __restrict__ dinv, int E)
{
    size_t tid = (size_t)blockIdx.x * blockDim.x + threadIdx.x;
    int e = (int)(tid >> 5);
    if (e >= E) return;
    int f = ((int)tid & 31) * 4;
    int s = src[e], d = dst[e];
    float norm = dinv[s] * dinv[d];
    float4 hv = *(const float4*)&H[(size_t)s * DIM + f];
    float* o = &O[(size_t)d * DIM + f];
    unsafeAtomicAdd(o + 0, hv.x * norm);
    unsafeAtomicAdd(o + 1, hv.y * norm);
    unsafeAtomicAdd(o + 2, hv.z * norm);
    unsafeAtomicAdd(o + 3, hv.w * norm);
}

// ---------------- pooling + head ----------------
// out[g] = mean_{i in g} dot(relu(H[i] + b2), Wlin) + blin
// (linear commutes with mean) — one wave per node, scalar atomic per node.

__global__ __launch_bounds__(256) void pool_kernel(
    const float* __restrict__ H, const float* __restrict__ b2,
    const float* __restrict__ wlin, const int* __restrict__ batch,
    float* __restrict__ sums, float* __restrict__ cnt, int N)
{
    int wave = threadIdx.x >> 6;
    int lane = threadIdx.x & 63;
    int node = blockIdx.x * 4 + wave;
    if (node >= N) return;
    float h0 = H[(size_t)node * DIM + lane];
    float h1 = H[(size_t)node * DIM + 64 + lane];
    float bb0 = b2[lane];
    float bb1 = b2[64 + lane];
    float w0 = wlin[lane];
    float w1 = wlin[64 + lane];
    float v = fmaxf(h0 + bb0, 0.f) * w0 + fmaxf(h1 + bb1, 0.f) * w1;
    #pragma unroll
    for (int m = 32; m >= 1; m >>= 1) v += __shfl_xor(v, m, 64);
    if (lane == 0) {
        int g = batch[node];
        unsafeAtomicAdd(&sums[g], v);
        unsafeAtomicAdd(&cnt[g], 1.0f);
    }
}

__global__ void final_kernel(const float* __restrict__ sums,
                             const float* __restrict__ cnt,
                             const float* __restrict__ blin,
                             float* __restrict__ out, int G)
{
    int g = blockIdx.x * blockDim.x + threadIdx.x;
    if (g < G) {
        out[g] = sums[g] / fmaxf(cnt[g], 1.0f) + blin[0];
    }
}

// ---------------- launch ----------------

extern "C" void kernel_launch(void* const* d_in, const int* in_sizes, int n_in,
                              void* d_out, int out_size, void* d_ws, size_t ws_size,
                              hipStream_t stream)
{
    const float* x    = (const float*)d_in[0];
    const int*   src  = (const int*)d_in[1];
    const int*   dst  = (const int*)d_in[2];
    const int*   batch= (const int*)d_in[3];
    // d_in[4] = n_graphs scalar (== out_size)
    const float* W1   = (const float*)d_in[5];
    const float* b1   = (const float*)d_in[6];
    const float* W2   = (const float*)d_in[7];
    const float* b2   = (const float*)d_in[8];
    const float* wlin = (const float*)d_in[9];
    const float* blin = (const float*)d_in[10];
    float* out = (float*)d_out;

    const int N = in_sizes[0] / DIM;
    const int E = in_sizes[1];
    const int G = out_size;

    float* ws   = (float*)d_ws;
    size_t nf   = (size_t)N * DIM;
    float* B0   = ws;                 // N*128 fp32
    float* B1   = ws + nf;            // N*128 fp32
    float* dinv = ws + 2 * nf;        // N fp32
    float* sums = dinv + N;           // G fp32
    float* cnt  = sums + G;           // G fp32

    // degree / dinv (deg includes self-loop)
    deg_init<<<(N + 255) / 256, 256, 0, stream>>>(dinv, N);
    edge_deg<<<(E + 255) / 256, 256, 0, stream>>>(dinv, dst, E);
    deg_fin <<<(N + 255) / 256, 256, 0, stream>>>(dinv, N);

    const int gblocks = (N + 63) / 64;
    const int nthr32  = N * 32;                 // per-node float4 kernels
    const long long ethr = (long long)E * 32;   // per-edge float4 kernels

    // layer 1: h1 = x @ W1 ; agg1 = D^-1/2 A_hat D^-1/2 h1
    gemm_nodes<0><<<gblocks, 64, 0, stream>>>(x, nullptr, W1, B0, N);
    self_loop<<<(nthr32 + 255) / 256, 256, 0, stream>>>(B0, B1, dinv, N);
    edge_agg<<<(int)((ethr + 255) / 256), 256, 0, stream>>>(B0, B1, src, dst, dinv, E);

    // layer 2: h2 = relu(agg1 + b1) @ W2 ; agg2 likewise
    gemm_nodes<1><<<gblocks, 64, 0, stream>>>(B1, b1, W2, B0, N);
    self_loop<<<(nthr32 + 255) / 256, 256, 0, stream>>>(B0, B1, dinv, N);
    edge_agg<<<(int)((ethr + 255) / 256), 256, 0, stream>>>(B0, B1, src, dst, dinv, E);

    // pooling + linear head
    hipMemsetAsync(sums, 0, sizeof(float) * 2 * (size_t)G, stream);  // sums & cnt
    pool_kernel<<<(N + 3) / 4, 256, 0, stream>>>(B1, b2, wlin, batch, sums, cnt, N);
    final_kernel<<<(G + 255) / 256, 256, 0, stream>>>(sums, cnt, blin, out, G);
}

// Round 4
// 627.314 us; speedup vs baseline: 5.0198x; 5.0198x over previous
//
#include <hip/hip_runtime.h>
#include <hip/hip_bf16.h>

#define DIM 128

// ======================= CSR-gather path =======================

__global__ void edge_count(int* __restrict__ deg, const int* __restrict__ dst, int E) {
    int e = blockIdx.x * blockDim.x + threadIdx.x;
    if (e < E) atomicAdd(&deg[dst[e]], 1);
}

// Per-wave inclusive scan of degrees -> one global-cursor atomic per wave.
// Bucket order across waves is nondeterministic but buckets are disjoint and
// contiguous, which is all the gather needs.
__global__ __launch_bounds__(256) void alloc_offsets(
    const int* __restrict__ deg, int* __restrict__ start, int* __restrict__ end_,
    int* __restrict__ cursor, float* __restrict__ dinv, int* total, int N)
{
    int i = blockIdx.x * blockDim.x + threadIdx.x;
    int lane = threadIdx.x & 63;
    int d = (i < N) ? deg[i] : 0;
    int pre = d;
    #pragma unroll
    for (int off = 1; off < 64; off <<= 1) {
        int v = __shfl_up(pre, off, 64);
        if (lane >= off) pre += v;
    }
    int waveTot = __shfl(pre, 63, 64);
    int base = 0;
    if (lane == 63) base = atomicAdd(total, waveTot);
    base = __shfl(base, 63, 64);
    if (i < N) {
        int st = base + pre - d;
        start[i]  = st;
        end_[i]   = st + d;
        cursor[i] = st;
        dinv[i]   = rsqrtf((float)(d + 1));   // +1 self-loop
    }
}

__global__ void scatter_edges(const int* __restrict__ src, const int* __restrict__ dst,
                              const float* __restrict__ dinv, int* __restrict__ cursor,
                              int* __restrict__ csr_src, float* __restrict__ csr_nrm, int E)
{
    int e = blockIdx.x * blockDim.x + threadIdx.x;
    if (e >= E) return;
    int s = src[e], d = dst[e];
    int p = atomicAdd(&cursor[d], 1);
    csr_src[p] = s;
    csr_nrm[p] = dinv[s] * dinv[d];
}

// One wave per dst node: acc = dinv^2*H[node] + sum nrm*H[src].
// FUSE_POOL: instead of writing O, apply relu(acc+b2)·wlin and reduce into
// per-graph sums (the layer-2 aggregate is only consumed by the pool).
template<int FUSE_POOL>
__global__ __launch_bounds__(256) void gather_agg(
    const float* __restrict__ H, float* __restrict__ O,
    const int* __restrict__ csr_src, const float* __restrict__ csr_nrm,
    const int* __restrict__ start, const int* __restrict__ end_,
    const float* __restrict__ dinv, int N,
    const float* __restrict__ b2, const float* __restrict__ wlin,
    const int* __restrict__ batch, float* __restrict__ sums, float* __restrict__ cnt)
{
    int wave = threadIdx.x >> 6;
    int lane = threadIdx.x & 63;
    int node = blockIdx.x * 4 + wave;
    if (node >= N) return;

    int st = start[node], en = end_[node];
    float di = dinv[node];
    float nn = di * di;
    float2 acc;
    {
        float2 hv = *(const float2*)&H[(size_t)node * DIM + lane * 2];
        acc.x = hv.x * nn;
        acc.y = hv.y * nn;
    }
    int j = st;
    for (; j + 1 < en; j += 2) {          // unroll x2: both row loads in flight
        int   s0 = csr_src[j],   s1 = csr_src[j + 1];
        float n0 = csr_nrm[j],   n1 = csr_nrm[j + 1];
        float2 h0 = *(const float2*)&H[(size_t)s0 * DIM + lane * 2];
        float2 h1 = *(const float2*)&H[(size_t)s1 * DIM + lane * 2];
        acc.x = fmaf(h0.x, n0, acc.x);  acc.x = fmaf(h1.x, n1, acc.x);
        acc.y = fmaf(h0.y, n0, acc.y);  acc.y = fmaf(h1.y, n1, acc.y);
    }
    if (j < en) {
        int s0 = csr_src[j]; float n0 = csr_nrm[j];
        float2 h0 = *(const float2*)&H[(size_t)s0 * DIM + lane * 2];
        acc.x = fmaf(h0.x, n0, acc.x);
        acc.y = fmaf(h0.y, n0, acc.y);
    }

    if (FUSE_POOL) {
        float v = fmaxf(acc.x + b2[lane * 2], 0.f)     * wlin[lane * 2]
                + fmaxf(acc.y + b2[lane * 2 + 1], 0.f) * wlin[lane * 2 + 1];
        #pragma unroll
        for (int m = 32; m >= 1; m >>= 1) v += __shfl_xor(v, m, 64);
        if (lane == 0) {
            int g = batch[node];
            unsafeAtomicAdd(&sums[g], v);
            unsafeAtomicAdd(&cnt[g], 1.0f);
        }
    } else {
        *(float2*)&O[(size_t)node * DIM + lane * 2] = acc;
    }
}

// ---------------- GEMM: Y[node][f] = sum_k X[node][k] * W[k][f] ----------------
// 256 threads / 64 nodes per block. LDS holds the tile transposed xs[k][node]
// (pad 65 -> conflict-free both ways). Thread (t): node = t&63, feature quarter
// q = t>>6 (wave-uniform -> W reads scalarize). MODE 1 fuses relu(x+bias).

template<int MODE>
__global__ __launch_bounds__(256) void gemm_nodes(
    const float* __restrict__ X,
    const float* __restrict__ bias,
    const float* __restrict__ W,   // [128][128] row-major (k, f)
    float* __restrict__ Y, int N)
{
    __shared__ float xs[DIM][65];
    const int t = threadIdx.x;
    const int node0 = blockIdx.x * 64;

    for (int idx = t; idx < 64 * DIM; idx += 256) {
        int r = idx >> 7;       // node row 0..63
        int c = idx & 127;      // feature col
        int node = node0 + r;
        float v = 0.f;
        if (node < N) {
            v = X[(size_t)node * DIM + c];
            if (MODE == 1) v = fmaxf(v + bias[c], 0.f);
        }
        xs[c][r] = v;
    }
    __syncthreads();

    const int node = node0 + (t & 63);
    const int q = t >> 6;          // wave-uniform
    const int f0 = q * 32;
    float acc[32];
    #pragma unroll
    for (int j = 0; j < 32; ++j) acc[j] = 0.f;

    for (int k = 0; k < DIM; ++k) {
        float xk = xs[k][t & 63];
        const float* wrow = W + (size_t)k * DIM + f0;   // uniform -> s_load
        #pragma unroll
        for (int j = 0; j < 32; ++j) acc[j] = fmaf(xk, wrow[j], acc[j]);
    }
    if (node < N) {
        float4* outp = (float4*)&Y[(size_t)node * DIM + f0];
        #pragma unroll
        for (int j = 0; j < 8; ++j)
            outp[j] = make_float4(acc[j*4], acc[j*4+1], acc[j*4+2], acc[j*4+3]);
    }
}

__global__ void final_kernel(const float* __restrict__ sums,
                             const float* __restrict__ cnt,
                             const float* __restrict__ blin,
                             float* __restrict__ out, int G)
{
    int g = blockIdx.x * blockDim.x + threadIdx.x;
    if (g < G) out[g] = sums[g] / fmaxf(cnt[g], 1.0f) + blin[0];
}

// ======================= fallback (atomic) path =======================

__global__ void deg_init(float* deg, int n) {
    int i = blockIdx.x * blockDim.x + threadIdx.x;
    if (i < n) deg[i] = 1.0f;
}
__global__ void edge_deg(float* deg, const int* __restrict__ dst, int E) {
    int e = blockIdx.x * blockDim.x + threadIdx.x;
    if (e < E) unsafeAtomicAdd(&deg[dst[e]], 1.0f);
}
__global__ void deg_fin(float* deg, int n) {
    int i = blockIdx.x * blockDim.x + threadIdx.x;
    if (i < n) deg[i] = rsqrtf(deg[i]);
}
__global__ void self_loop(const float* __restrict__ H, float* __restrict__ O,
                          const float* __restrict__ dinv, int N)
{
    size_t tid = (size_t)blockIdx.x * blockDim.x + threadIdx.x;
    int i = (int)(tid >> 5);
    if (i >= N) return;
    int f = ((int)tid & 31) * 4;
    float di = dinv[i]; float nrm = di * di;
    float4 hv = *(const float4*)&H[(size_t)i * DIM + f];
    *(float4*)&O[(size_t)i * DIM + f] =
        make_float4(hv.x*nrm, hv.y*nrm, hv.z*nrm, hv.w*nrm);
}
__global__ void edge_agg(const float* __restrict__ H, float* __restrict__ O,
                         const int* __restrict__ src, const int* __restrict__ dst,
                         const float* __restrict__ dinv, int E)
{
    size_t tid = (size_t)blockIdx.x * blockDim.x + threadIdx.x;
    int e = (int)(tid >> 5);
    if (e >= E) return;
    int f = ((int)tid & 31) * 4;
    int s = src[e], d = dst[e];
    float norm = dinv[s] * dinv[d];
    float4 hv = *(const float4*)&H[(size_t)s * DIM + f];
    float* o = &O[(size_t)d * DIM + f];
    unsafeAtomicAdd(o + 0, hv.x * norm);
    unsafeAtomicAdd(o + 1, hv.y * norm);
    unsafeAtomicAdd(o + 2, hv.z * norm);
    unsafeAtomicAdd(o + 3, hv.w * norm);
}
__global__ __launch_bounds__(256) void pool_kernel(
    const float* __restrict__ H, const float* __restrict__ b2,
    const float* __restrict__ wlin, const int* __restrict__ batch,
    float* __restrict__ sums, float* __restrict__ cnt, int N)
{
    int wave = threadIdx.x >> 6;
    int lane = threadIdx.x & 63;
    int node = blockIdx.x * 4 + wave;
    if (node >= N) return;
    float v = fmaxf(H[(size_t)node*DIM + lane] + b2[lane], 0.f) * wlin[lane]
            + fmaxf(H[(size_t)node*DIM + 64 + lane] + b2[64+lane], 0.f) * wlin[64+lane];
    #pragma unroll
    for (int m = 32; m >= 1; m >>= 1) v += __shfl_xor(v, m, 64);
    if (lane == 0) {
        int g = batch[node];
        unsafeAtomicAdd(&sums[g], v);
        unsafeAtomicAdd(&cnt[g], 1.0f);
    }
}

// ======================= launch =======================

extern "C" void kernel_launch(void* const* d_in, const int* in_sizes, int n_in,
                              void* d_out, int out_size, void* d_ws, size_t ws_size,
                              hipStream_t stream)
{
    const float* x    = (const float*)d_in[0];
    const int*   src  = (const int*)d_in[1];
    const int*   dst  = (const int*)d_in[2];
    const int*   batch= (const int*)d_in[3];
    const float* W1   = (const float*)d_in[5];
    const float* b1   = (const float*)d_in[6];
    const float* W2   = (const float*)d_in[7];
    const float* b2   = (const float*)d_in[8];
    const float* wlin = (const float*)d_in[9];
    const float* blin = (const float*)d_in[10];
    float* out = (float*)d_out;

    const int N = in_sizes[0] / DIM;
    const int E = in_sizes[1];
    const int G = out_size;

    float* ws = (float*)d_ws;
    size_t nf = (size_t)N * DIM;

    // layout: B0, B1, dinv(N), sums(G), cnt(G), deg/cursor(N), start(N),
    //         end(N), csr_src(E), csr_nrm(E), total(1)
    float* B0    = ws;
    float* B1    = B0 + nf;
    float* dinv  = B1 + nf;
    float* sums  = dinv + N;
    float* cnt   = sums + G;
    int*   deg_c = (int*)(cnt + G);
    int*   start = deg_c + N;
    int*   end_  = start + N;
    int*   csrs  = end_ + N;
    float* csrn  = (float*)(csrs + E);
    int*   total = (int*)(csrn + E);
    size_t need_bytes = ((size_t)(total + 1) - (size_t)ws);

    const int gblocks = (N + 63) / 64;
    const int eblocks = (E + 255) / 256;

    if (ws_size >= need_bytes) {
        // ---- CSR build (once, reused by both layers) ----
        hipMemsetAsync(deg_c, 0, sizeof(int) * (size_t)N, stream);
        hipMemsetAsync(total, 0, sizeof(int), stream);
        hipMemsetAsync(sums, 0, sizeof(float) * 2 * (size_t)G, stream);
        edge_count<<<eblocks, 256, 0, stream>>>(deg_c, dst, E);
        alloc_offsets<<<(N + 255) / 256, 256, 0, stream>>>(deg_c, start, end_, deg_c,
                                                           dinv, total, N);
        scatter_edges<<<eblocks, 256, 0, stream>>>(src, dst, dinv, deg_c, csrs, csrn, E);

        // ---- layer 1 ----
        gemm_nodes<0><<<gblocks, 256, 0, stream>>>(x, nullptr, W1, B0, N);
        gather_agg<0><<<(N + 3) / 4, 256, 0, stream>>>(B0, B1, csrs, csrn, start, end_,
                                                       dinv, N, nullptr, nullptr,
                                                       nullptr, nullptr, nullptr);
        // ---- layer 2 (gather fused with pooling) ----
        gemm_nodes<1><<<gblocks, 256, 0, stream>>>(B1, b1, W2, B0, N);
        gather_agg<1><<<(N + 3) / 4, 256, 0, stream>>>(B0, nullptr, csrs, csrn, start,
                                                       end_, dinv, N, b2, wlin,
                                                       batch, sums, cnt);
        final_kernel<<<(G + 255) / 256, 256, 0, stream>>>(sums, cnt, blin, out, G);
    } else {
        // ---- fallback: atomic scatter path ----
        const int nthr32 = N * 32;
        const long long ethr = (long long)E * 32;
        deg_init<<<(N + 255) / 256, 256, 0, stream>>>(dinv, N);
        edge_deg<<<eblocks, 256, 0, stream>>>(dinv, dst, E);
        deg_fin <<<(N + 255) / 256, 256, 0, stream>>>(dinv, N);
        gemm_nodes<0><<<gblocks, 256, 0, stream>>>(x, nullptr, W1, B0, N);
        self_loop<<<(nthr32 + 255) / 256, 256, 0, stream>>>(B0, B1, dinv, N);
        edge_agg<<<(int)((ethr + 255) / 256), 256, 0, stream>>>(B0, B1, src, dst, dinv, E);
        gemm_nodes<1><<<gblocks, 256, 0, stream>>>(B1, b1, W2, B0, N);
        self_loop<<<(nthr32 + 255) / 256, 256, 0, stream>>>(B0, B1, dinv, N);
        edge_agg<<<(int)((ethr + 255) / 256), 256, 0, stream>>>(B0, B1, src, dst, dinv, E);
        hipMemsetAsync(sums, 0, sizeof(float) * 2 * (size_t)G, stream);
        pool_kernel<<<(N + 3) / 4, 256, 0, stream>>>(B1, b2, wlin, batch, sums, cnt, N);
        final_kernel<<<(G + 255) / 256, 256, 0, stream>>>(sums, cnt, blin, out, G);
    }
}

// Round 5
// 414.558 us; speedup vs baseline: 7.5960x; 1.5132x over previous
//
#include <hip/hip_runtime.h>
#include <hip/hip_bf16.h>

#define DIM 128

// ======================= CSR build =======================

__global__ void edge_count(int* __restrict__ deg, const int* __restrict__ dst, int E) {
    int e = blockIdx.x * blockDim.x + threadIdx.x;
    if (e < E) atomicAdd(&deg[dst[e]], 1);
}

__global__ __launch_bounds__(256) void alloc_offsets(
    const int* __restrict__ deg, int* __restrict__ start, int* __restrict__ end_,
    int* __restrict__ cursor, float* __restrict__ dinv, int* total, int N)
{
    int i = blockIdx.x * blockDim.x + threadIdx.x;
    int lane = threadIdx.x & 63;
    int d = (i < N) ? deg[i] : 0;
    int pre = d;
    #pragma unroll
    for (int off = 1; off < 64; off <<= 1) {
        int v = __shfl_up(pre, off, 64);
        if (lane >= off) pre += v;
    }
    int waveTot = __shfl(pre, 63, 64);
    int base = 0;
    if (lane == 63) base = atomicAdd(total, waveTot);
    base = __shfl(base, 63, 64);
    if (i < N) {
        int st = base + pre - d;
        start[i]  = st;
        end_[i]   = st + d;
        cursor[i] = st;
        dinv[i]   = rsqrtf((float)(d + 1));   // +1 self-loop
    }
}

__global__ void scatter_edges(const int* __restrict__ src, const int* __restrict__ dst,
                              const float* __restrict__ dinv, int* __restrict__ cursor,
                              int* __restrict__ csr_src, float* __restrict__ csr_nrm, int E)
{
    int e = blockIdx.x * blockDim.x + threadIdx.x;
    if (e >= E) return;
    int s = src[e], d = dst[e];
    int p = atomicAdd(&cursor[d], 1);
    csr_src[p] = s;
    csr_nrm[p] = dinv[s] * dinv[d];
}

// ======================= gather aggregation =======================
// One wave per dst node: acc = dinv^2*H[node] + sum nrm*H[src], float2/lane.
// Unroll x4 keeps 4 independent row-loads in flight (latency-bound loop).
template<int FUSE_POOL>
__global__ __launch_bounds__(256) void gather_agg(
    const float* __restrict__ H, float* __restrict__ O,
    const int* __restrict__ csr_src, const float* __restrict__ csr_nrm,
    const int* __restrict__ start, const int* __restrict__ end_,
    const float* __restrict__ dinv, int N,
    const float* __restrict__ b2, const float* __restrict__ wlin,
    const int* __restrict__ batch, float* __restrict__ sums, float* __restrict__ cnt)
{
    int wave = threadIdx.x >> 6;
    int lane = threadIdx.x & 63;
    int node = blockIdx.x * 4 + wave;
    if (node >= N) return;

    int st = start[node], en = end_[node];
    float di = dinv[node];
    float nn = di * di;
    float2 acc;
    {
        float2 hv = *(const float2*)&H[(size_t)node * DIM + lane * 2];
        acc.x = hv.x * nn;
        acc.y = hv.y * nn;
    }
    int j = st;
    for (; j + 3 < en; j += 4) {
        int   s0 = csr_src[j],     s1 = csr_src[j + 1];
        int   s2 = csr_src[j + 2], s3 = csr_src[j + 3];
        float n0 = csr_nrm[j],     n1 = csr_nrm[j + 1];
        float n2 = csr_nrm[j + 2], n3 = csr_nrm[j + 3];
        float2 h0 = *(const float2*)&H[(size_t)s0 * DIM + lane * 2];
        float2 h1 = *(const float2*)&H[(size_t)s1 * DIM + lane * 2];
        float2 h2 = *(const float2*)&H[(size_t)s2 * DIM + lane * 2];
        float2 h3 = *(const float2*)&H[(size_t)s3 * DIM + lane * 2];
        acc.x = fmaf(h0.x, n0, acc.x);  acc.y = fmaf(h0.y, n0, acc.y);
        acc.x = fmaf(h1.x, n1, acc.x);  acc.y = fmaf(h1.y, n1, acc.y);
        acc.x = fmaf(h2.x, n2, acc.x);  acc.y = fmaf(h2.y, n2, acc.y);
        acc.x = fmaf(h3.x, n3, acc.x);  acc.y = fmaf(h3.y, n3, acc.y);
    }
    for (; j < en; ++j) {
        int s0 = csr_src[j]; float n0 = csr_nrm[j];
        float2 h0 = *(const float2*)&H[(size_t)s0 * DIM + lane * 2];
        acc.x = fmaf(h0.x, n0, acc.x);
        acc.y = fmaf(h0.y, n0, acc.y);
    }

    if (FUSE_POOL) {
        float v = fmaxf(acc.x + b2[lane * 2], 0.f)     * wlin[lane * 2]
                + fmaxf(acc.y + b2[lane * 2 + 1], 0.f) * wlin[lane * 2 + 1];
        #pragma unroll
        for (int m = 32; m >= 1; m >>= 1) v += __shfl_xor(v, m, 64);
        if (lane == 0) {
            int g = batch[node];
            unsafeAtomicAdd(&sums[g], v);
            unsafeAtomicAdd(&cnt[g], 1.0f);
        }
    } else {
        *(float2*)&O[(size_t)node * DIM + lane * 2] = acc;
    }
}

// ======================= GEMM =======================
// Y[node][f] = sum_k X'[node][k] * W[k][f],  X' = MODE ? relu(X+bias) : X.
// Classic LDS-tiled outer product: BM=64 nodes, BN=128 feats, BK=32.
// 256 threads; thread tile = 8 nodes x 4 features (32 acc VGPRs).
// As[kk][node] (pad 72), Bs[kk][feat] (pad 132) -> 16B-aligned rows.

template<int MODE>
__global__ __launch_bounds__(256) void gemm_nodes(
    const float* __restrict__ X,
    const float* __restrict__ bias,
    const float* __restrict__ W,   // [128][128] row-major (k, f)
    float* __restrict__ Y, int N)
{
    __shared__ float As[32][72];
    __shared__ float Bs[32][132];
    const int t = threadIdx.x;
    const int node0 = blockIdx.x * 64;
    const int tx = t & 31;          // feature quad: f0 = tx*4
    const int ty = t >> 5;          // node oct:    n0 = ty*8
    const int f0 = tx * 4;
    const int n0 = ty * 8;

    float acc[8][4];
    #pragma unroll
    for (int i = 0; i < 8; ++i)
        #pragma unroll
        for (int j = 0; j < 4; ++j) acc[i][j] = 0.f;

    const int sr  = t >> 3;         // staging node row 0..31
    const int sc4 = (t & 7) * 4;    // staging k quad

    for (int k0 = 0; k0 < DIM; k0 += 32) {
        // ---- stage A: 64 nodes x 32 k, transposed into As[kk][node] ----
        #pragma unroll
        for (int half = 0; half < 2; ++half) {
            int r = sr + half * 32;
            int node = node0 + r;
            float v[4] = {0.f, 0.f, 0.f, 0.f};
            if (node < N)
                *(float4*)v = *(const float4*)&X[(size_t)node * DIM + k0 + sc4];
            if (MODE == 1) {
                float bv[4];
                *(float4*)bv = *(const float4*)&bias[k0 + sc4];
                #pragma unroll
                for (int i = 0; i < 4; ++i) v[i] = fmaxf(v[i] + bv[i], 0.f);
                if (node >= N) { v[0]=v[1]=v[2]=v[3]=0.f; }
            }
            #pragma unroll
            for (int i = 0; i < 4; ++i) As[sc4 + i][r] = v[i];
        }
        // ---- stage B: 32 k x 128 f ----
        #pragma unroll
        for (int i = 0; i < 4; ++i) {
            int kk = (t >> 5) + i * 8;
            float4 wv = *(const float4*)&W[(size_t)(k0 + kk) * DIM + f0];
            *(float4*)&Bs[kk][f0] = wv;
        }
        __syncthreads();

        // ---- outer-product accumulate ----
        #pragma unroll 4
        for (int kk = 0; kk < 32; ++kk) {
            float4 a0 = *(const float4*)&As[kk][n0];
            float4 a1 = *(const float4*)&As[kk][n0 + 4];
            float4 b  = *(const float4*)&Bs[kk][f0];
            float av[8] = {a0.x,a0.y,a0.z,a0.w,a1.x,a1.y,a1.z,a1.w};
            float bv[4] = {b.x,b.y,b.z,b.w};
            #pragma unroll
            for (int i = 0; i < 8; ++i)
                #pragma unroll
                for (int j = 0; j < 4; ++j)
                    acc[i][j] = fmaf(av[i], bv[j], acc[i][j]);
        }
        __syncthreads();
    }

    #pragma unroll
    for (int i = 0; i < 8; ++i) {
        int node = node0 + n0 + i;
        if (node < N)
            *(float4*)&Y[(size_t)node * DIM + f0] =
                make_float4(acc[i][0], acc[i][1], acc[i][2], acc[i][3]);
    }
}

__global__ void final_kernel(const float* __restrict__ sums,
                             const float* __restrict__ cnt,
                             const float* __restrict__ blin,
                             float* __restrict__ out, int G)
{
    int g = blockIdx.x * blockDim.x + threadIdx.x;
    if (g < G) out[g] = sums[g] / fmaxf(cnt[g], 1.0f) + blin[0];
}

// ======================= fallback (atomic) path =======================

__global__ void deg_init(float* deg, int n) {
    int i = blockIdx.x * blockDim.x + threadIdx.x;
    if (i < n) deg[i] = 1.0f;
}
__global__ void edge_deg(float* deg, const int* __restrict__ dst, int E) {
    int e = blockIdx.x * blockDim.x + threadIdx.x;
    if (e < E) unsafeAtomicAdd(&deg[dst[e]], 1.0f);
}
__global__ void deg_fin(float* deg, int n) {
    int i = blockIdx.x * blockDim.x + threadIdx.x;
    if (i < n) deg[i] = rsqrtf(deg[i]);
}
__global__ void self_loop(const float* __restrict__ H, float* __restrict__ O,
                          const float* __restrict__ dinv, int N)
{
    size_t tid = (size_t)blockIdx.x * blockDim.x + threadIdx.x;
    int i = (int)(tid >> 5);
    if (i >= N) return;
    int f = ((int)tid & 31) * 4;
    float di = dinv[i]; float nrm = di * di;
    float4 hv = *(const float4*)&H[(size_t)i * DIM + f];
    *(float4*)&O[(size_t)i * DIM + f] =
        make_float4(hv.x*nrm, hv.y*nrm, hv.z*nrm, hv.w*nrm);
}
__global__ void edge_agg(const float* __restrict__ H, float* __restrict__ O,
                         const int* __restrict__ src, const int* __restrict__ dst,
                         const float* __restrict__ dinv, int E)
{
    size_t tid = (size_t)blockIdx.x * blockDim.x + threadIdx.x;
    int e = (int)(tid >> 5);
    if (e >= E) return;
    int f = ((int)tid & 31) * 4;
    int s = src[e], d = dst[e];
    float norm = dinv[s] * dinv[d];
    float4 hv = *(const float4*)&H[(size_t)s * DIM + f];
    float* o = &O[(size_t)d * DIM + f];
    unsafeAtomicAdd(o + 0, hv.x * norm);
    unsafeAtomicAdd(o + 1, hv.y * norm);
    unsafeAtomicAdd(o + 2, hv.z * norm);
    unsafeAtomicAdd(o + 3, hv.w * norm);
}
__global__ __launch_bounds__(256) void pool_kernel(
    const float* __restrict__ H, const float* __restrict__ b2,
    const float* __restrict__ wlin, const int* __restrict__ batch,
    float* __restrict__ sums, float* __restrict__ cnt, int N)
{
    int wave = threadIdx.x >> 6;
    int lane = threadIdx.x & 63;
    int node = blockIdx.x * 4 + wave;
    if (node >= N) return;
    float v = fmaxf(H[(size_t)node*DIM + lane] + b2[lane], 0.f) * wlin[lane]
            + fmaxf(H[(size_t)node*DIM + 64 + lane] + b2[64+lane], 0.f) * wlin[64+lane];
    #pragma unroll
    for (int m = 32; m >= 1; m >>= 1) v += __shfl_xor(v, m, 64);
    if (lane == 0) {
        int g = batch[node];
        unsafeAtomicAdd(&sums[g], v);
        unsafeAtomicAdd(&cnt[g], 1.0f);
    }
}

// ======================= launch =======================

extern "C" void kernel_launch(void* const* d_in, const int* in_sizes, int n_in,
                              void* d_out, int out_size, void* d_ws, size_t ws_size,
                              hipStream_t stream)
{
    const float* x    = (const float*)d_in[0];
    const int*   src  = (const int*)d_in[1];
    const int*   dst  = (const int*)d_in[2];
    const int*   batch= (const int*)d_in[3];
    const float* W1   = (const float*)d_in[5];
    const float* b1   = (const float*)d_in[6];
    const float* W2   = (const float*)d_in[7];
    const float* b2   = (const float*)d_in[8];
    const float* wlin = (const float*)d_in[9];
    const float* blin = (const float*)d_in[10];
    float* out = (float*)d_out;

    const int N = in_sizes[0] / DIM;
    const int E = in_sizes[1];
    const int G = out_size;

    float* ws = (float*)d_ws;
    size_t nf = (size_t)N * DIM;

    float* B0    = ws;
    float* B1    = B0 + nf;
    float* dinv  = B1 + nf;
    float* sums  = dinv + N;
    float* cnt   = sums + G;
    int*   deg_c = (int*)(cnt + G);
    int*   start = deg_c + N;
    int*   end_  = start + N;
    int*   csrs  = end_ + N;
    float* csrn  = (float*)(csrs + E);
    int*   total = (int*)(csrn + E);
    size_t need_bytes = ((size_t)(total + 1) - (size_t)ws);

    const int gblocks = (N + 63) / 64;
    const int eblocks = (E + 255) / 256;

    if (ws_size >= need_bytes) {
        // ---- CSR build (once, reused by both layers) ----
        hipMemsetAsync(deg_c, 0, sizeof(int) * (size_t)N, stream);
        hipMemsetAsync(total, 0, sizeof(int), stream);
        hipMemsetAsync(sums, 0, sizeof(float) * 2 * (size_t)G, stream);
        edge_count<<<eblocks, 256, 0, stream>>>(deg_c, dst, E);
        alloc_offsets<<<(N + 255) / 256, 256, 0, stream>>>(deg_c, start, end_, deg_c,
                                                           dinv, total, N);
        scatter_edges<<<eblocks, 256, 0, stream>>>(src, dst, dinv, deg_c, csrs, csrn, E);

        // ---- layer 1 ----
        gemm_nodes<0><<<gblocks, 256, 0, stream>>>(x, nullptr, W1, B0, N);
        gather_agg<0><<<(N + 3) / 4, 256, 0, stream>>>(B0, B1, csrs, csrn, start, end_,
                                                       dinv, N, nullptr, nullptr,
                                                       nullptr, nullptr, nullptr);
        // ---- layer 2 (gather fused with pooling) ----
        gemm_nodes<1><<<gblocks, 256, 0, stream>>>(B1, b1, W2, B0, N);
        gather_agg<1><<<(N + 3) / 4, 256, 0, stream>>>(B0, nullptr, csrs, csrn, start,
                                                       end_, dinv, N, b2, wlin,
                                                       batch, sums, cnt);
        final_kernel<<<(G + 255) / 256, 256, 0, stream>>>(sums, cnt, blin, out, G);
    } else {
        // ---- fallback: atomic scatter path ----
        const int nthr32 = N * 32;
        const long long ethr = (long long)E * 32;
        deg_init<<<(N + 255) / 256, 256, 0, stream>>>(dinv, N);
        edge_deg<<<eblocks, 256, 0, stream>>>(dinv, dst, E);
        deg_fin <<<(N + 255) / 256, 256, 0, stream>>>(dinv, N);
        gemm_nodes<0><<<gblocks, 256, 0, stream>>>(x, nullptr, W1, B0, N);
        self_loop<<<(nthr32 + 255) / 256, 256, 0, stream>>>(B0, B1, dinv, N);
        edge_agg<<<(int)((ethr + 255) / 256), 256, 0, stream>>>(B0, B1, src, dst, dinv, E);
        gemm_nodes<1><<<gblocks, 256, 0, stream>>>(B1, b1, W2, B0, N);
        self_loop<<<(nthr32 + 255) / 256, 256, 0, stream>>>(B0, B1, dinv, N);
        edge_agg<<<(int)((ethr + 255) / 256), 256, 0, stream>>>(B0, B1, src, dst, dinv, E);
        hipMemsetAsync(sums, 0, sizeof(float) * 2 * (size_t)G, stream);
        pool_kernel<<<(N + 3) / 4, 256, 0, stream>>>(B1, b2, wlin, batch, sums, cnt, N);
        final_kernel<<<(G + 255) / 256, 256, 0, stream>>>(sums, cnt, blin, out, G);
    }
}